// Round 14
// baseline (5019.107 us; speedup 1.0000x reference)
//
#include <hip/hip_runtime.h>
#include <hip/hip_bf16.h>
#include <stdint.h>

// Problem constants (from reference)
#define V_SZ 32000
#define D_SZ 1024          // = K
#define M_SZ 8192          // B*S = 4*2048

typedef __attribute__((ext_vector_type(8))) short bf16x8;
typedef __attribute__((ext_vector_type(4))) float f32x4;
typedef __attribute__((ext_vector_type(16))) float f32x16;

static __device__ __forceinline__ unsigned short f32_to_bf16_rne(float f) {
    union { float f; uint32_t u; } v; v.f = f;
    uint32_t u = v.u;
    uint32_t lsb = (u >> 16) & 1;
    u += 0x7fffu + lsb;
    return (unsigned short)(u >> 16);
}

// ---------------------------------------------------------------------------
// Kernel 1: embedding gather. One block per output row, float4 copy.
__global__ void gather_rows(const int* __restrict__ ids,
                            const float* __restrict__ table,
                            float* __restrict__ out) {
    int row = blockIdx.x;
    int id  = ids[row];
    const f32x4* src = (const f32x4*)(table + (size_t)id * D_SZ);
    f32x4*       dst = (f32x4*)(out + (size_t)row * D_SZ);
    __builtin_nontemporal_store(src[threadIdx.x], &dst[threadIdx.x]);
}

// ---------------------------------------------------------------------------
// Kernel 2: cast embeds f32 -> bf16 (A matrix [M][K]), 8 elems/thread.
__global__ void cast_f32_bf16(const float* __restrict__ in,
                              unsigned short* __restrict__ out, int n8) {
    int i = blockIdx.x * blockDim.x + threadIdx.x;
    int stride = gridDim.x * blockDim.x;
    for (; i < n8; i += stride) {
        const float4* p = (const float4*)(in + (size_t)i * 8);
        float4 a = p[0], b = p[1];
        union { unsigned short s[8]; uint4 v; } r;
        r.s[0] = f32_to_bf16_rne(a.x); r.s[1] = f32_to_bf16_rne(a.y);
        r.s[2] = f32_to_bf16_rne(a.z); r.s[3] = f32_to_bf16_rne(a.w);
        r.s[4] = f32_to_bf16_rne(b.x); r.s[5] = f32_to_bf16_rne(b.y);
        r.s[6] = f32_to_bf16_rne(b.z); r.s[7] = f32_to_bf16_rne(b.w);
        ((uint4*)out)[i] = r.v;
    }
}

// ---------------------------------------------------------------------------
// Kernel 3: transpose+cast out_weight [K=1024][V=32000] f32 -> Bt [V][K] bf16.
__global__ void transpose_cast(const float* __restrict__ w,
                               unsigned short* __restrict__ bt) {
    __shared__ unsigned short tile[32][34];
    int n0 = blockIdx.x * 32;          // column block in V
    int k0 = blockIdx.y * 32;          // row block in K
    int r = threadIdx.x >> 5;          // 0..7
    int c = threadIdx.x & 31;          // 0..31
#pragma unroll
    for (int rr = 0; rr < 32; rr += 8) {
        float v = w[(size_t)(k0 + r + rr) * V_SZ + (n0 + c)];
        tile[c][r + rr] = f32_to_bf16_rne(v);
    }
    __syncthreads();
    int nl = threadIdx.x >> 3;         // 0..31
    int ks = threadIdx.x & 7;          // 0..7  (4 bf16 = 8B per thread)
    union { unsigned short s[4]; uint2 v; } r2;
#pragma unroll
    for (int j = 0; j < 4; ++j) r2.s[j] = tile[nl][ks * 4 + j];
    ((uint2*)(bt + (size_t)(n0 + nl) * D_SZ + k0))[ks] = r2.v;
}

// ---------------------------------------------------------------------------
// Kernel 4: PERSISTENT wave-specialized bf16 GEMM.
// 768 threads = 12 waves: 0-7 COMPUTE (2/SIMD -- the proven TLP minimum),
// 8-11 PRODUCERS (1/SIMD). Producers own ALL global_load_lds + counted
// vmcnt(8) (stage s+2, retire s+1; vmcnt(0) tail). Compute waves execute
// ZERO vmcnt waits: their FIFO holds only nontemporal C-stores which drain
// in background -- this removes the store-FIFO poisoning of counted waits
// (in r8-r13 every post-epilogue wait drained a 256KB/CU store burst,
// ~25k cyc, ~8 of every 16 steps).
// Tile 256x256, BK=32 slabs (32 KB), TRIPLE buffered (96 KB LDS, 1 blk/CU),
// one s_barrier per step, k-split LDS layout (0 conflicts r1-r13).
// XCD map (r8): xcd owns 4 bm (2 MB A in L2); bn = q0 + 8r lockstep sweep.
#define BM 256
#define BN 256
#define BKs 32
#define SLAB 32768          // A [4 hi][256 row][16B] + B [4 hi][256 col][16B]

static __device__ __forceinline__ void gload_lds16(const unsigned short* g, void* lds) {
    __builtin_amdgcn_global_load_lds(
        (const __attribute__((address_space(1))) void*)g,
        (__attribute__((address_space(3))) void*)lds,
        16, 0, 0);
}

__global__ __launch_bounds__(768)
void gemm_wspec(const unsigned short* __restrict__ A,
                const unsigned short* __restrict__ Bt,
                float* __restrict__ C) {
    __shared__ __align__(16) char lds[3 * SLAB];   // 96 KB

    const int tid  = threadIdx.x;
    const int lane = tid & 63;
    const int w    = tid >> 6;           // 0..11

    const int bid = blockIdx.x;          // 256 blocks, 1/CU
    const int xcd = bid & 7;
    const int jb  = bid >> 3;            // 0..31
    const int bm0 = (xcd * 4 + (jb & 3)) * BM;
    const int q0  = jb >> 2;             // 0..7
    const int ntiles = (q0 < 5) ? 16 : 15;   // bn = q0 + 8r <= 124
    const int S   = ntiles * 32;         // BK=32 steps

    if (w >= 8) {
        // --------------------------- producers ---------------------------
        const int pt = tid - 512;        // 0..255
        const unsigned short* aRow = A + (size_t)(bm0 + pt) * D_SZ;  // invariant
        const unsigned short* bCur = Bt + (size_t)(q0 * BN + pt) * D_SZ;
        const size_t bnstride = (size_t)8 * BN * D_SZ;
        const int dstO = pt * 16;

#define PSTAGE(s2, bufo) do { \
    const int k0_ = ((s2) & 31) * 32; \
    char* bp_ = (char*)lds + (bufo); \
    const unsigned short* pa_ = aRow + k0_; \
    gload_lds16(pa_,      bp_ +         dstO); \
    gload_lds16(pa_ + 8,  bp_ + 4096  + dstO); \
    gload_lds16(pa_ + 16, bp_ + 8192  + dstO); \
    gload_lds16(pa_ + 24, bp_ + 12288 + dstO); \
    const unsigned short* pb_ = bCur + k0_; \
    gload_lds16(pb_,      bp_ + 16384 + dstO); \
    gload_lds16(pb_ + 8,  bp_ + 20480 + dstO); \
    gload_lds16(pb_ + 16, bp_ + 24576 + dstO); \
    gload_lds16(pb_ + 24, bp_ + 28672 + dstO); \
} while (0)

        // Prologue: stage steps 0,1; retire step 0; barrier (1:1 w/ compute).
        PSTAGE(0, 0);
        PSTAGE(1, SLAB);
        asm volatile("s_waitcnt vmcnt(8)" ::: "memory");
        __builtin_amdgcn_sched_barrier(0);
        __builtin_amdgcn_s_barrier();

        int bufS = 2 * SLAB;             // buffer for step s+2
        for (int s = 0; s < S; ++s) {
            const int s2 = s + 2;
            if (s2 < S) {
                if ((s2 & 31) == 0) bCur += bnstride;   // next bn tile
                PSTAGE(s2, bufS);
                asm volatile("s_waitcnt vmcnt(8)" ::: "memory");  // s+1 landed
            } else {
                asm volatile("s_waitcnt vmcnt(0)" ::: "memory");  // tail drain
            }
            __builtin_amdgcn_sched_barrier(0);
            __builtin_amdgcn_s_barrier();
            bufS += SLAB; if (bufS == 3 * SLAB) bufS = 0;
        }
#undef PSTAGE
    } else {
        // --------------------------- compute -----------------------------
        const int wr = w >> 2;           // 0..1 (128-row half)
        const int wc = w & 3;            // 0..3 (64-col quarter)
        const int hi2 = lane >> 5, l31 = lane & 31;
        const int aoff = (wr * 128 + l31) * 16;          // + mg*512
        const int boff = 16384 + (wc * 64 + l31) * 16;   // + ng*512

        f32x16 acc[4][2];
#pragma unroll
        for (int mg = 0; mg < 4; ++mg)
#pragma unroll
            for (int ng = 0; ng < 2; ++ng)
#pragma unroll
                for (int e = 0; e < 16; ++e) acc[mg][ng][e] = 0.0f;

        __builtin_amdgcn_s_barrier();    // match producer prologue barrier

        int bufo = 0;
        for (int s = 0; s < S; ++s) {
            const char* base = (const char*)lds + bufo;

            bf16x8 a[4][2], b[2][2];
#pragma unroll
            for (int mg = 0; mg < 4; ++mg)
#pragma unroll
                for (int kk = 0; kk < 2; ++kk)
                    a[mg][kk] = *(const bf16x8*)(base + (kk * 2 + hi2) * 4096
                                                 + aoff + mg * 512);
#pragma unroll
            for (int ng = 0; ng < 2; ++ng)
#pragma unroll
                for (int kk = 0; kk < 2; ++kk)
                    b[ng][kk] = *(const bf16x8*)(base + (kk * 2 + hi2) * 4096
                                                 + boff + ng * 512);

            __builtin_amdgcn_s_setprio(1);
#pragma unroll
            for (int kk = 0; kk < 2; ++kk)
#pragma unroll
                for (int mg = 0; mg < 4; ++mg)
#pragma unroll
                    for (int ng = 0; ng < 2; ++ng)
                        acc[mg][ng] = __builtin_amdgcn_mfma_f32_32x32x16_bf16(
                            a[mg][kk], b[ng][kk], acc[mg][ng], 0, 0, 0);
            __builtin_amdgcn_s_setprio(0);
            __builtin_amdgcn_sched_barrier(0);
            __builtin_amdgcn_s_barrier();
            bufo += SLAB; if (bufo == 3 * SLAB) bufo = 0;

            if ((s & 31) == 31) {
                // Tile epilogue: nt stores; NEVER vmcnt-waited (compute path
                // has no waits) -> drains under the next tile's compute.
                const int r = s >> 5;
                const int ccol0 = (q0 + 8 * r) * BN + wc * 64 + l31;
                const int crow0 = bm0 + wr * 128 + hi2 * 4;
#pragma unroll
                for (int mg = 0; mg < 4; ++mg)
#pragma unroll
                    for (int ng = 0; ng < 2; ++ng) {
                        float* basep = C + (size_t)(crow0 + mg * 32) * V_SZ
                                       + ccol0 + ng * 32;
#pragma unroll
                        for (int e = 0; e < 16; ++e) {
                            const int roff = (e & 3) + 8 * (e >> 2);
                            __builtin_nontemporal_store(acc[mg][ng][e],
                                                        basep + (size_t)roff * V_SZ);
                        }
#pragma unroll
                        for (int e = 0; e < 16; ++e) acc[mg][ng][e] = 0.0f;
                    }
            }
        }
    }
}

// ---------------------------------------------------------------------------
extern "C" void kernel_launch(void* const* d_in, const int* in_sizes, int n_in,
                              void* d_out, int out_size, void* d_ws, size_t ws_size,
                              hipStream_t stream) {
    const int*   ids        = (const int*)d_in[0];       // [B,S] = 8192
    const float* embeds     = (const float*)d_in[1];     // [B,S,D]
    const float* in_weight  = (const float*)d_in[2];     // [V,D]
    const float* out_weight = (const float*)d_in[3];     // [D,V]

    float* out_embedded = (float*)d_out;                       // M*D floats
    float* out_logits   = (float*)d_out + (size_t)M_SZ * D_SZ; // M*V floats

    // workspace: A bf16 [M][K] (16 MB) + Bt bf16 [V][K] (64 MB) = ~82 MB
    unsigned short* Abf  = (unsigned short*)d_ws;
    unsigned short* Btbf = Abf + (size_t)M_SZ * D_SZ;

    gather_rows<<<M_SZ, 256, 0, stream>>>(ids, in_weight, out_embedded);
    cast_f32_bf16<<<2048, 256, 0, stream>>>(embeds, Abf, M_SZ * D_SZ / 8);
    transpose_cast<<<dim3(V_SZ / 32, D_SZ / 32), 256, 0, stream>>>(out_weight, Btbf);
    gemm_wspec<<<dim3(256), 768, 0, stream>>>(Abf, Btbf, out_logits);
}

// Round 15
// 774.005 us; speedup vs baseline: 6.4846x; 6.4846x over previous
//
#include <hip/hip_runtime.h>
#include <hip/hip_bf16.h>
#include <stdint.h>

// Problem constants (from reference)
#define V_SZ 32000
#define D_SZ 1024          // = K
#define M_SZ 8192          // B*S = 4*2048

typedef __attribute__((ext_vector_type(8))) short bf16x8;
typedef __attribute__((ext_vector_type(4))) float f32x4;
typedef __attribute__((ext_vector_type(16))) float f32x16;

static __device__ __forceinline__ unsigned short f32_to_bf16_rne(float f) {
    union { float f; uint32_t u; } v; v.f = f;
    uint32_t u = v.u;
    uint32_t lsb = (u >> 16) & 1;
    u += 0x7fffu + lsb;
    return (unsigned short)(u >> 16);
}

// ---------------------------------------------------------------------------
// Kernel 1: embedding gather. One block per output row, float4 copy.
__global__ void gather_rows(const int* __restrict__ ids,
                            const float* __restrict__ table,
                            float* __restrict__ out) {
    int row = blockIdx.x;
    int id  = ids[row];
    const f32x4* src = (const f32x4*)(table + (size_t)id * D_SZ);
    f32x4*       dst = (f32x4*)(out + (size_t)row * D_SZ);
    __builtin_nontemporal_store(src[threadIdx.x], &dst[threadIdx.x]);
}

// ---------------------------------------------------------------------------
// Kernel 2: cast embeds f32 -> bf16 (A matrix [M][K]), 8 elems/thread.
__global__ void cast_f32_bf16(const float* __restrict__ in,
                              unsigned short* __restrict__ out, int n8) {
    int i = blockIdx.x * blockDim.x + threadIdx.x;
    int stride = gridDim.x * blockDim.x;
    for (; i < n8; i += stride) {
        const float4* p = (const float4*)(in + (size_t)i * 8);
        float4 a = p[0], b = p[1];
        union { unsigned short s[8]; uint4 v; } r;
        r.s[0] = f32_to_bf16_rne(a.x); r.s[1] = f32_to_bf16_rne(a.y);
        r.s[2] = f32_to_bf16_rne(a.z); r.s[3] = f32_to_bf16_rne(a.w);
        r.s[4] = f32_to_bf16_rne(b.x); r.s[5] = f32_to_bf16_rne(b.y);
        r.s[6] = f32_to_bf16_rne(b.z); r.s[7] = f32_to_bf16_rne(b.w);
        ((uint4*)out)[i] = r.v;
    }
}

// ---------------------------------------------------------------------------
// Kernel 3: transpose+cast out_weight [K=1024][V=32000] f32 -> Bt [V][K] bf16.
__global__ void transpose_cast(const float* __restrict__ w,
                               unsigned short* __restrict__ bt) {
    __shared__ unsigned short tile[32][34];
    int n0 = blockIdx.x * 32;          // column block in V
    int k0 = blockIdx.y * 32;          // row block in K
    int r = threadIdx.x >> 5;          // 0..7
    int c = threadIdx.x & 31;          // 0..31
#pragma unroll
    for (int rr = 0; rr < 32; rr += 8) {
        float v = w[(size_t)(k0 + r + rr) * V_SZ + (n0 + c)];
        tile[c][r + rr] = f32_to_bf16_rne(v);
    }
    __syncthreads();
    int nl = threadIdx.x >> 3;         // 0..31
    int ks = threadIdx.x & 7;          // 0..7  (4 bf16 = 8B per thread)
    union { unsigned short s[4]; uint2 v; } r2;
#pragma unroll
    for (int j = 0; j < 4; ++j) r2.s[j] = tile[nl][ks * 4 + j];
    ((uint2*)(bt + (size_t)(n0 + nl) * D_SZ + k0))[ks] = r2.v;
}

// ---------------------------------------------------------------------------
// Kernel 4: PERSISTENT bf16 GEMM -- EXACT r8 champion structure (680 us,
// MfmaUtil 36%) with ONE change: C stores are NORMAL (write-back) instead of
// nontemporal. Rationale: vmcnt is a shared in-order 6-bit FIFO; the 128
// nt-store dwords/thread per tile epilogue ack at HBM rate (~25k cyc/CU),
// and the next tile's first counted vmcnt(6) must drain them all first --
// an unavoidable serial tax (can't count past 63). Normal stores ack at L2
// (~4-5k cyc) -> the drain mostly vanishes. (r14's wave-specialization
// alternative is structurally infeasible: one kernel-wide VGPR allocation
// means producers inherit the compute waves' budget; 12-wave blocks cap at
// ~170 VGPR < 196 needed -> acc spilled -> 17 GB scratch traffic.)
// 256x256 tile, BK=64, 8 waves (2Mx4N), 32x32x16 MFMA, 128 KiB LDS dbuf,
// k-split layout (0 bank conflicts). 4-phase K-step, counted vmcnt(6).
// XCD map: xcd owns 4 bm (2 MB A slice, L2-pinned); bn = q0 + 8r lockstep.
#define BM 256
#define BN 256
#define BK 64
#define NSTEP (D_SZ / BK)   // 16 K-steps per tile

static __device__ __forceinline__ void gload_lds16(const unsigned short* g, void* lds) {
    __builtin_amdgcn_global_load_lds(
        (const __attribute__((address_space(1))) void*)g,
        (__attribute__((address_space(3))) void*)lds,
        16, 0, 0);
}

__global__ __launch_bounds__(512, 2)
void gemm_persist(const unsigned short* __restrict__ A,
                  const unsigned short* __restrict__ Bt,
                  float* __restrict__ C) {
    __shared__ __align__(16) char lds[131072];

    const int tid  = threadIdx.x;
    const int lane = tid & 63;
    const int w    = tid >> 6;           // wave 0..7
    const int wr   = w >> 2;             // 0..1  (A half)
    const int wc   = w & 3;              // 0..3  (B: half = wc>>1, sub = wc&1)

    const int bid = blockIdx.x;
    const int xcd = bid & 7;
    const int jb  = bid >> 3;            // 0..31
    const int bm0 = (xcd * 4 + (jb & 3)) * BM;
    const int q0  = jb >> 2;             // 0..7
    const int ntiles = (bid < 160) ? 16 : 15;

    // staging thread mapping: (hi0,row0) and (hi0+4,row0)
    const int hi0  = tid >> 7;           // 0..3
    const int row0 = tid & 127;          // 0..127
    const int dstO = hi0 * 2048 + row0 * 16;
    const unsigned short* gA  = A  + (size_t)(bm0 + row0) * D_SZ + hi0 * 8;  // rows 0-127
    const unsigned short* gA1 = gA + (size_t)128 * D_SZ;                     // rows 128-255
    const unsigned short* gBc = Bt + (size_t)(q0 * BN + row0) * D_SZ + hi0 * 8;
    const size_t bn_stride = (size_t)8 * BN * D_SZ;   // bn advances 8 tiles per r

#define STG(ptr, slotbase) do { \
    gload_lds16((ptr),      (char*)lds + (slotbase) + dstO); \
    gload_lds16((ptr) + 32, (char*)lds + (slotbase) + dstO + 8192); } while (0)

    // Prologue: tile0 step0 fully + step1 minus A1(1); wait oldest 8.
    STG(gBc,                           32768);
    STG(gBc + (size_t)128 * D_SZ,      32768 + 16384);
    STG(gA,                            0);
    STG(gA1,                           16384);
    STG(gBc + 64,                      65536 + 32768);
    STG(gBc + (size_t)128 * D_SZ + 64, 65536 + 32768 + 16384);
    STG(gA + 64,                       65536);
    asm volatile("s_waitcnt vmcnt(6)" ::: "memory");
    __builtin_amdgcn_s_barrier();

    f32x16 acc[4][2];
#pragma unroll
    for (int m = 0; m < 4; ++m)
#pragma unroll
        for (int n = 0; n < 2; ++n)
#pragma unroll
            for (int e = 0; e < 16; ++e) acc[m][n][e] = 0.0f;

    bf16x8 a[2][4];       // [mi2][kk] current QM quadrant
    bf16x8 b[2][4];       // [qn][kk]  both QN quadrants live

    // 32x32x16 frag: row/col = lane&31, k-group = kk*2 + (lane>>5)
    const int base_f = (lane >> 5) * 2048 + (lane & 31) * 16;

#define LDA(mi2, kk, QM) (*(const bf16x8*)(abuf + (kk) * 4096 + ((QM) * 2 + (mi2)) * 512 + base_f))
#define LDB(ni, kk)      (*(const bf16x8*)(bbuf + (kk) * 4096 + (ni) * 512 + base_f))

#define MFMA_Q(QM, QN) \
    __builtin_amdgcn_s_setprio(1); \
    _Pragma("unroll") for (int kk = 0; kk < 4; ++kk) \
    _Pragma("unroll") for (int mi2 = 0; mi2 < 2; ++mi2) \
        acc[(QM) * 2 + mi2][QN] = __builtin_amdgcn_mfma_f32_32x32x16_bf16( \
            a[mi2][kk], b[QN][kk], acc[(QM) * 2 + mi2][QN], 0, 0, 0); \
    __builtin_amdgcn_s_setprio(0);

#define MIDSYNC \
    __builtin_amdgcn_sched_barrier(0); \
    __builtin_amdgcn_s_barrier();

    const int crow = bm0 + wr * 128 + (lane >> 5) * 4;
    const int ccol_f = wc * 64 + (lane & 31);

    for (int r = 0; r < ntiles; ++r) {
        const unsigned short* gBn = gBc + bn_stride;
        const bool last = (r == ntiles - 1);

        for (int t = 0; t < NSTEP; ++t) {
            const int   dbuf = (t & 1) << 16;
            const char* abuf = (const char*)lds + dbuf + wr * 16384;
            const char* bbuf = (const char*)lds + dbuf + 32768
                               + (wc >> 1) * 16384 + (wc & 1) * 1024;
            const int nslot = (dbuf ^ 65536);

            // ---- P0: (QM0,QN0); stage A1(step t+1) rows 128-255
            a[0][0] = LDA(0, 0, 0); a[0][1] = LDA(0, 1, 0);
            a[0][2] = LDA(0, 2, 0); a[0][3] = LDA(0, 3, 0);
            a[1][0] = LDA(1, 0, 0); a[1][1] = LDA(1, 1, 0);
            a[1][2] = LDA(1, 2, 0); a[1][3] = LDA(1, 3, 0);
            b[0][0] = LDB(0, 0); b[0][1] = LDB(0, 1);
            b[0][2] = LDB(0, 2); b[0][3] = LDB(0, 3);
            if (!(last && t == 15)) STG(gA1 + ((t + 1) & 15) * 64, nslot + 16384);
            MIDSYNC;
            MFMA_Q(0, 0);
            __builtin_amdgcn_s_barrier();

            // ---- P1: (QM0,QN1)
            b[1][0] = LDB(1, 0); b[1][1] = LDB(1, 1);
            b[1][2] = LDB(1, 2); b[1][3] = LDB(1, 3);
            MIDSYNC;
            MFMA_Q(0, 1);
            __builtin_amdgcn_s_barrier();

            // ---- P2: (QM1,QN1); stage B0(step t+2) (next tile when t>=14)
            a[0][0] = LDA(0, 0, 1); a[0][1] = LDA(0, 1, 1);
            a[0][2] = LDA(0, 2, 1); a[0][3] = LDA(0, 3, 1);
            a[1][0] = LDA(1, 0, 1); a[1][1] = LDA(1, 1, 1);
            a[1][2] = LDA(1, 2, 1); a[1][3] = LDA(1, 3, 1);
            if (t < 14 || !last) {
                const unsigned short* pb = (t < 14) ? gBc + (t + 2) * 64
                                                    : gBn + (t - 14) * 64;
                STG(pb, dbuf + 32768);
            }
            MIDSYNC;
            MFMA_Q(1, 1);
            __builtin_amdgcn_s_barrier();

            // ---- P3: (QM1,QN0); stage B1(t+2), A0(t+2)
            if (t < 14 || !last) {
                const unsigned short* pb = (t < 14) ? gBc + (t + 2) * 64
                                                    : gBn + (t - 14) * 64;
                STG(pb + (size_t)128 * D_SZ, dbuf + 32768 + 16384);
                STG(gA + ((t + 2) & 15) * 64, dbuf);
            }
            MFMA_Q(1, 0);
            if (last && t >= 14) { asm volatile("s_waitcnt vmcnt(0)" ::: "memory"); }
            else                 { asm volatile("s_waitcnt vmcnt(6)" ::: "memory"); }
            __builtin_amdgcn_s_barrier();
        }

        // Epilogue for tile r. NORMAL stores (ack at L2, not HBM) so the
        // next tile's counted vmcnt(6) doesn't serially drain them to HBM.
        const int ccol = (q0 + 8 * r) * BN + ccol_f;
#pragma unroll
        for (int mi = 0; mi < 4; ++mi)
#pragma unroll
            for (int ni = 0; ni < 2; ++ni) {
                float* base = C + (size_t)(crow + mi * 32) * V_SZ + (ccol + ni * 32);
#pragma unroll
                for (int e = 0; e < 16; ++e) {
                    int roff = (e & 3) + 8 * (e >> 2);
                    base[(size_t)roff * V_SZ] = acc[mi][ni][e];
                }
            }
#pragma unroll
        for (int m = 0; m < 4; ++m)
#pragma unroll
            for (int n = 0; n < 2; ++n)
#pragma unroll
                for (int e = 0; e < 16; ++e) acc[m][n][e] = 0.0f;

        gBc = gBn;
    }
#undef STG
#undef LDA
#undef LDB
#undef MFMA_Q
#undef MIDSYNC
}

// ---------------------------------------------------------------------------
extern "C" void kernel_launch(void* const* d_in, const int* in_sizes, int n_in,
                              void* d_out, int out_size, void* d_ws, size_t ws_size,
                              hipStream_t stream) {
    const int*   ids        = (const int*)d_in[0];       // [B,S] = 8192
    const float* embeds     = (const float*)d_in[1];     // [B,S,D]
    const float* in_weight  = (const float*)d_in[2];     // [V,D]
    const float* out_weight = (const float*)d_in[3];     // [D,V]

    float* out_embedded = (float*)d_out;                       // M*D floats
    float* out_logits   = (float*)d_out + (size_t)M_SZ * D_SZ; // M*V floats

    // workspace: A bf16 [M][K] (16 MB) + Bt bf16 [V][K] (64 MB) = ~82 MB
    unsigned short* Abf  = (unsigned short*)d_ws;
    unsigned short* Btbf = Abf + (size_t)M_SZ * D_SZ;

    gather_rows<<<M_SZ, 256, 0, stream>>>(ids, in_weight, out_embedded);
    cast_f32_bf16<<<2048, 256, 0, stream>>>(embeds, Abf, M_SZ * D_SZ / 8);
    transpose_cast<<<dim3(V_SZ / 32, D_SZ / 32), 256, 0, stream>>>(out_weight, Btbf);
    gemm_persist<<<dim3(256), 512, 0, stream>>>(Abf, Btbf, out_logits);
}

// Round 16
// 770.313 us; speedup vs baseline: 6.5157x; 1.0048x over previous
//
#include <hip/hip_runtime.h>
#include <hip/hip_bf16.h>
#include <stdint.h>

// Problem constants (from reference)
#define V_SZ 32000
#define D_SZ 1024          // = K
#define M_SZ 8192          // B*S = 4*2048

typedef __attribute__((ext_vector_type(8))) short bf16x8;
typedef __attribute__((ext_vector_type(4))) float f32x4;
typedef __attribute__((ext_vector_type(16))) float f32x16;

static __device__ __forceinline__ unsigned short f32_to_bf16_rne(float f) {
    union { float f; uint32_t u; } v; v.f = f;
    uint32_t u = v.u;
    uint32_t lsb = (u >> 16) & 1;
    u += 0x7fffu + lsb;
    return (unsigned short)(u >> 16);
}

// ---------------------------------------------------------------------------
// Kernel 1: embedding gather. One block per output row, float4 copy.
__global__ void gather_rows(const int* __restrict__ ids,
                            const float* __restrict__ table,
                            float* __restrict__ out) {
    int row = blockIdx.x;
    int id  = ids[row];
    const f32x4* src = (const f32x4*)(table + (size_t)id * D_SZ);
    f32x4*       dst = (f32x4*)(out + (size_t)row * D_SZ);
    __builtin_nontemporal_store(src[threadIdx.x], &dst[threadIdx.x]);
}

// ---------------------------------------------------------------------------
// Kernel 2: cast embeds f32 -> bf16 (A matrix [M][K]), 8 elems/thread.
__global__ void cast_f32_bf16(const float* __restrict__ in,
                              unsigned short* __restrict__ out, int n8) {
    int i = blockIdx.x * blockDim.x + threadIdx.x;
    int stride = gridDim.x * blockDim.x;
    for (; i < n8; i += stride) {
        const float4* p = (const float4*)(in + (size_t)i * 8);
        float4 a = p[0], b = p[1];
        union { unsigned short s[8]; uint4 v; } r;
        r.s[0] = f32_to_bf16_rne(a.x); r.s[1] = f32_to_bf16_rne(a.y);
        r.s[2] = f32_to_bf16_rne(a.z); r.s[3] = f32_to_bf16_rne(a.w);
        r.s[4] = f32_to_bf16_rne(b.x); r.s[5] = f32_to_bf16_rne(b.y);
        r.s[6] = f32_to_bf16_rne(b.z); r.s[7] = f32_to_bf16_rne(b.w);
        ((uint4*)out)[i] = r.v;
    }
}

// ---------------------------------------------------------------------------
// Kernel 3: transpose+cast out_weight [K=1024][V=32000] f32 -> Bt [V][K] bf16.
__global__ void transpose_cast(const float* __restrict__ w,
                               unsigned short* __restrict__ bt) {
    __shared__ unsigned short tile[32][34];
    int n0 = blockIdx.x * 32;          // column block in V
    int k0 = blockIdx.y * 32;          // row block in K
    int r = threadIdx.x >> 5;          // 0..7
    int c = threadIdx.x & 31;          // 0..31
#pragma unroll
    for (int rr = 0; rr < 32; rr += 8) {
        float v = w[(size_t)(k0 + r + rr) * V_SZ + (n0 + c)];
        tile[c][r + rr] = f32_to_bf16_rne(v);
    }
    __syncthreads();
    int nl = threadIdx.x >> 3;         // 0..31
    int ks = threadIdx.x & 7;          // 0..7  (4 bf16 = 8B per thread)
    union { unsigned short s[4]; uint2 v; } r2;
#pragma unroll
    for (int j = 0; j < 4; ++j) r2.s[j] = tile[nl][ks * 4 + j];
    ((uint2*)(bt + (size_t)(n0 + nl) * D_SZ + k0))[ks] = r2.v;
}

// ---------------------------------------------------------------------------
// Kernel 4: PERSISTENT bf16 GEMM (r8 champion, nt stores) with the staging
// REORDERED so every load needed by the first post-epilogue step precedes
// the C-store burst in the vmcnt FIFO:
//   - ALL staging of step t+2 happens in P2 (B0) and P3 (B1, A0, A1);
//     P0 stages nothing. Steady-state wait = vmcnt(8) (16 outstanding,
//     retires step t+1).
//   - At a tile boundary steps 0' and 1' are fully staged BEFORE the
//     epilogue, so t=0's wait can be vmcnt(63): it retires step-1's loads
//     plus only ~73 of the 128 nt stores; the rest drain in background
//     (r8's vmcnt(6) at t=0 forced a FULL ~25k-cyc store drain per tile,
//     ~156 us total). First tile uses vmcnt(8) (no stores yet).
// 256x256 tile, BK=64, 8 waves (2Mx4N), 32x32x16 MFMA, 128 KiB LDS dbuf,
// k-split layout (0 bank conflicts r1-r15). XCD map: xcd owns 4 bm (2 MB
// A slice, L2-pinned); bn = q0 + 8r cross-XCD lockstep sweep.
#define BM 256
#define BN 256
#define BK 64
#define NSTEP (D_SZ / BK)   // 16 K-steps per tile

static __device__ __forceinline__ void gload_lds16(const unsigned short* g, void* lds) {
    __builtin_amdgcn_global_load_lds(
        (const __attribute__((address_space(1))) void*)g,
        (__attribute__((address_space(3))) void*)lds,
        16, 0, 0);
}

__global__ __launch_bounds__(512, 2)
void gemm_persist(const unsigned short* __restrict__ A,
                  const unsigned short* __restrict__ Bt,
                  float* __restrict__ C) {
    __shared__ __align__(16) char lds[131072];

    const int tid  = threadIdx.x;
    const int lane = tid & 63;
    const int w    = tid >> 6;           // wave 0..7
    const int wr   = w >> 2;             // 0..1  (A half)
    const int wc   = w & 3;              // 0..3  (B: half = wc>>1, sub = wc&1)

    const int bid = blockIdx.x;
    const int xcd = bid & 7;
    const int jb  = bid >> 3;            // 0..31
    const int bm0 = (xcd * 4 + (jb & 3)) * BM;
    const int q0  = jb >> 2;             // 0..7
    const int ntiles = (bid < 160) ? 16 : 15;

    // staging thread mapping: (hi0,row0) and (hi0+4,row0)
    const int hi0  = tid >> 7;           // 0..3
    const int row0 = tid & 127;          // 0..127
    const int dstO = hi0 * 2048 + row0 * 16;
    const unsigned short* gA  = A  + (size_t)(bm0 + row0) * D_SZ + hi0 * 8;  // rows 0-127
    const unsigned short* gA1 = gA + (size_t)128 * D_SZ;                     // rows 128-255
    const unsigned short* gBc = Bt + (size_t)(q0 * BN + row0) * D_SZ + hi0 * 8;
    const size_t bn_stride = (size_t)8 * BN * D_SZ;   // bn advances 8 tiles per r

#define STG(ptr, slotbase) do { \
    gload_lds16((ptr),      (char*)lds + (slotbase) + dstO); \
    gload_lds16((ptr) + 32, (char*)lds + (slotbase) + dstO + 8192); } while (0)

    // Prologue: step0 (8 loads) then step1 (8 loads); retire step0; barrier.
    STG(gA,                            0);
    STG(gA1,                           16384);
    STG(gBc,                           32768);
    STG(gBc + (size_t)128 * D_SZ,      49152);
    STG(gA + 64,                       65536);
    STG(gA1 + 64,                      65536 + 16384);
    STG(gBc + 64,                      65536 + 32768);
    STG(gBc + (size_t)128 * D_SZ + 64, 65536 + 49152);
    asm volatile("s_waitcnt vmcnt(8)" ::: "memory");
    __builtin_amdgcn_s_barrier();

    f32x16 acc[4][2];
#pragma unroll
    for (int m = 0; m < 4; ++m)
#pragma unroll
        for (int n = 0; n < 2; ++n)
#pragma unroll
            for (int e = 0; e < 16; ++e) acc[m][n][e] = 0.0f;

    bf16x8 a[2][4];       // [mi2][kk] current QM quadrant
    bf16x8 b[2][4];       // [qn][kk]  both QN quadrants live

    // 32x32x16 frag: row/col = lane&31, k-group = kk*2 + (lane>>5)
    const int base_f = (lane >> 5) * 2048 + (lane & 31) * 16;

#define LDA(mi2, kk, QM) (*(const bf16x8*)(abuf + (kk) * 4096 + ((QM) * 2 + (mi2)) * 512 + base_f))
#define LDB(ni, kk)      (*(const bf16x8*)(bbuf + (kk) * 4096 + (ni) * 512 + base_f))

#define MFMA_Q(QM, QN) \
    __builtin_amdgcn_s_setprio(1); \
    _Pragma("unroll") for (int kk = 0; kk < 4; ++kk) \
    _Pragma("unroll") for (int mi2 = 0; mi2 < 2; ++mi2) \
        acc[(QM) * 2 + mi2][QN] = __builtin_amdgcn_mfma_f32_32x32x16_bf16( \
            a[mi2][kk], b[QN][kk], acc[(QM) * 2 + mi2][QN], 0, 0, 0); \
    __builtin_amdgcn_s_setprio(0);

#define MIDSYNC \
    __builtin_amdgcn_sched_barrier(0); \
    __builtin_amdgcn_s_barrier();

    const int crow = bm0 + wr * 128 + (lane >> 5) * 4;
    const int ccol_f = wc * 64 + (lane & 31);

    for (int r = 0; r < ntiles; ++r) {
        const unsigned short* gBn = gBc + bn_stride;
        const bool last = (r == ntiles - 1);

        for (int t = 0; t < NSTEP; ++t) {
            const int   dbuf = (t & 1) << 16;
            const char* abuf = (const char*)lds + dbuf + wr * 16384;
            const char* bbuf = (const char*)lds + dbuf + 32768
                               + (wc >> 1) * 16384 + (wc & 1) * 1024;

            const bool stg = (t < 14) || !last;
            const unsigned short* pb = (t < 14) ? gBc + (t + 2) * 64
                                                : gBn + (t - 14) * 64;
            const int ka2 = ((t + 2) & 15) * 64;

            // ---- P0: (QM0,QN0); no staging
            a[0][0] = LDA(0, 0, 0); a[0][1] = LDA(0, 1, 0);
            a[0][2] = LDA(0, 2, 0); a[0][3] = LDA(0, 3, 0);
            a[1][0] = LDA(1, 0, 0); a[1][1] = LDA(1, 1, 0);
            a[1][2] = LDA(1, 2, 0); a[1][3] = LDA(1, 3, 0);
            b[0][0] = LDB(0, 0); b[0][1] = LDB(0, 1);
            b[0][2] = LDB(0, 2); b[0][3] = LDB(0, 3);
            MIDSYNC;
            MFMA_Q(0, 0);
            __builtin_amdgcn_s_barrier();

            // ---- P1: (QM0,QN1)
            b[1][0] = LDB(1, 0); b[1][1] = LDB(1, 1);
            b[1][2] = LDB(1, 2); b[1][3] = LDB(1, 3);
            MIDSYNC;
            MFMA_Q(0, 1);
            __builtin_amdgcn_s_barrier();

            // ---- P2: (QM1,QN1); stage B0(t+2) (B0 slot readers done in P0/P1)
            a[0][0] = LDA(0, 0, 1); a[0][1] = LDA(0, 1, 1);
            a[0][2] = LDA(0, 2, 1); a[0][3] = LDA(0, 3, 1);
            a[1][0] = LDA(1, 0, 1); a[1][1] = LDA(1, 1, 1);
            a[1][2] = LDA(1, 2, 1); a[1][3] = LDA(1, 3, 1);
            if (stg) STG(pb, dbuf + 32768);
            MIDSYNC;
            MFMA_Q(1, 1);
            __builtin_amdgcn_s_barrier();

            // ---- P3: (QM1,QN0); stage B1(t+2), A0(t+2), A1(t+2)
            //      (A1 slot's readers = this step's P2 QM1 reads, complete)
            if (stg) {
                STG(pb + (size_t)128 * D_SZ, dbuf + 49152);
                STG(gA  + ka2, dbuf);
                STG(gA1 + ka2, dbuf + 16384);
            }
            MFMA_Q(1, 0);
            if (last && t >= 14) {
                asm volatile("s_waitcnt vmcnt(0)" ::: "memory");
            } else if (t == 0 && r > 0) {
                // post-epilogue: step-1 loads precede the 128 stores in the
                // FIFO; vmcnt(63) retires them + ~73 stores, leaving the
                // rest to drain in background under this tile's compute.
                asm volatile("s_waitcnt vmcnt(63)" ::: "memory");
            } else {
                asm volatile("s_waitcnt vmcnt(8)" ::: "memory");
            }
            __builtin_amdgcn_s_barrier();
        }

        // Epilogue for tile r (nt stores; steps 0'/1' already staged above).
        const int ccol = (q0 + 8 * r) * BN + ccol_f;
#pragma unroll
        for (int mi = 0; mi < 4; ++mi)
#pragma unroll
            for (int ni = 0; ni < 2; ++ni) {
                float* base = C + (size_t)(crow + mi * 32) * V_SZ + (ccol + ni * 32);
#pragma unroll
                for (int e = 0; e < 16; ++e) {
                    int roff = (e & 3) + 8 * (e >> 2);
                    __builtin_nontemporal_store(acc[mi][ni][e], base + (size_t)roff * V_SZ);
                }
            }
#pragma unroll
        for (int m = 0; m < 4; ++m)
#pragma unroll
            for (int n = 0; n < 2; ++n)
#pragma unroll
                for (int e = 0; e < 16; ++e) acc[m][n][e] = 0.0f;

        gBc = gBn;
    }
#undef STG
#undef LDA
#undef LDB
#undef MFMA_Q
#undef MIDSYNC
}

// ---------------------------------------------------------------------------
extern "C" void kernel_launch(void* const* d_in, const int* in_sizes, int n_in,
                              void* d_out, int out_size, void* d_ws, size_t ws_size,
                              hipStream_t stream) {
    const int*   ids        = (const int*)d_in[0];       // [B,S] = 8192
    const float* embeds     = (const float*)d_in[1];     // [B,S,D]
    const float* in_weight  = (const float*)d_in[2];     // [V,D]
    const float* out_weight = (const float*)d_in[3];     // [D,V]

    float* out_embedded = (float*)d_out;                       // M*D floats
    float* out_logits   = (float*)d_out + (size_t)M_SZ * D_SZ; // M*V floats

    // workspace: A bf16 [M][K] (16 MB) + Bt bf16 [V][K] (64 MB) = ~82 MB
    unsigned short* Abf  = (unsigned short*)d_ws;
    unsigned short* Btbf = Abf + (size_t)M_SZ * D_SZ;

    gather_rows<<<M_SZ, 256, 0, stream>>>(ids, in_weight, out_embedded);
    cast_f32_bf16<<<2048, 256, 0, stream>>>(embeds, Abf, M_SZ * D_SZ / 8);
    transpose_cast<<<dim3(V_SZ / 32, D_SZ / 32), 256, 0, stream>>>(out_weight, Btbf);
    gemm_persist<<<dim3(256), 512, 0, stream>>>(Abf, Btbf, out_logits);
}